// Round 8
// baseline (249.645 us; speedup 1.0000x reference)
//
#include <hip/hip_runtime.h>
#include <math.h>

// B=4096, IN=1024, H=2048, OUT=1024
// cosmic layer == broadcast prob[r] = (1/H)*(prod_{d,k} cos(cw[d,r,k]))^2
// Network = 6 fp16-MFMA GEMMs (16x16x32) with fused bias/relu/tanh epilogues.
//
// r8: max-TLP config. BM x BN tile, BK=32, 512 thr (8 waves WMxWN),
// tri-buffered LDS (72 KB) -> 2 blocks/CU = 4 waves/SIMD (two independent
// barrier domains per CU fill each other's stalls - m114/m97 mechanism).
// One barrier + counted vmcnt per K-tile (T4), lgkmcnt(0)+sched_barrier
// fence before MFMA cluster (rule 18), setprio (T5), XOR-swizzle
// both-sides (T2/rule 21, bank-uniform for 16-row frag reads), XCD (T1).

typedef _Float16 f16;
typedef _Float16 f16x8 __attribute__((ext_vector_type(8)));
typedef _Float16 f16x4 __attribute__((ext_vector_type(4)));
typedef float f32x4 __attribute__((ext_vector_type(4)));

#define GLD16(gp, lp) __builtin_amdgcn_global_load_lds( \
    (const __attribute__((address_space(1))) unsigned int*)(gp), \
    (__attribute__((address_space(3))) unsigned int*)(lp), 16, 0, 0)

__device__ __forceinline__ float tanh_fast(float x) {
  return 1.0f - 2.0f / (__expf(2.0f * x) + 1.0f);
}

// ---------------- fp32 -> fp16 cast ----------------
__global__ void cast_f32_f16(const float* __restrict__ in, f16* __restrict__ out, int n4) {
  int i = blockIdx.x * 256 + threadIdx.x;
  if (i < n4) {
    float4 v = ((const float4*)in)[i];
    f16x4 o = { (f16)v.x, (f16)v.y, (f16)v.z, (f16)v.w };
    ((f16x4*)out)[i] = o;
  }
}

// ------- merged cast+transpose, vectorized: 32(K) x 64(N) f32 tiles -------
struct TD { const float* src; f16* dst; int K; int N; };
struct TD6 { TD d[6]; };

__global__ void cast_transpose6(TD6 a) {
  TD d = a.d[blockIdx.z];
  const int bx = blockIdx.x * 64;   // N
  const int by = blockIdx.y * 32;   // K
  if (bx >= d.N || by >= d.K) return;
  __shared__ float tile[32][68];
  const int t = threadIdx.x;
#pragma unroll
  for (int pass = 0; pass < 2; ++pass) {
    int idx = t + pass * 256;
    int row = idx >> 4;
    int c4  = (idx & 15) * 4;
    float4 v = *(const float4*)&d.src[(size_t)(by + row) * d.N + bx + c4];
    *(float4*)&tile[row][c4] = v;
  }
  __syncthreads();
  const int nl = t >> 2;
  const int k8 = (t & 3) * 8;
  f16x8 o;
#pragma unroll
  for (int j = 0; j < 8; ++j) o[j] = (f16)tile[k8 + j][nl];
  *(f16x8*)&d.dst[(size_t)(bx + nl) * d.K + by + k8] = o;
}

// ---------------- cosmic prob, 2-pass, both tensors fused ----------------
__global__ void cosmic_pp2(const float* __restrict__ cw1, const float* __restrict__ cw2,
                           float* __restrict__ pp, int H) {
  int i = blockIdx.x * 256 + threadIdx.x;   // 0 .. 16H
  if (i >= 16 * H) return;
  const float* cw = (i < 8 * H) ? cw1 : cw2;
  int j = (i < 8 * H) ? i : i - 8 * H;
  const float* a = cw + (size_t)j * H;
  pp[i] = cosf(a[0]) * cosf(a[1]) * cosf(a[2]);
}
__global__ void cosmic_fin2(const float* __restrict__ pp, float* __restrict__ p1,
                            float* __restrict__ p2, int H) {
  int r = blockIdx.x * 256 + threadIdx.x;   // 0 .. 2H
  if (r >= 2 * H) return;
  int rr = (r < H) ? r : r - H;
  const float* base = pp + ((r < H) ? 0 : 8 * H);
  float p = 1.0f;
#pragma unroll
  for (int d = 0; d < 8; ++d) p *= base[d * H + rr];
  float v = p * p / (float)H;
  if (r < H) p1[rr] = v; else p2[rr] = v;
}

// ---------------- fp16 MFMA GEMM (16x16x32), BK=32, tri-buffer ----------------
// A: (M,K) f16 row-major. BT: (N,K) f16 row-major.
// EPI 0: relu->f16  1: tanh(+prob)->f16  2: relu->f32
// 512 thr = 8 waves arranged WM x WN; per-wave (BM/WM) x (BN/WN).
template <int EPI, int BM, int BN, int WM, int WN, int MINW>
__global__ __launch_bounds__(512, MINW)
void gemm_f16(const f16* __restrict__ A, const f16* __restrict__ BT,
              const float* __restrict__ bias, const float* __restrict__ prob,
              f16* __restrict__ Ch, float* __restrict__ Cf,
              int M, int N, int K, int GX) {
  constexpr int ASZ = BM * 32;            // f16 per A buffer (BK=32)
  constexpr int BSZ = BN * 32;            // f16 per B buffer
  constexpr int MR  = BM / WM / 16;       // A frag repeats per wave
  constexpr int NR  = BN / WN / 16;       // B frag repeats per wave
  constexpr int RA  = ASZ / 4096;         // A stage rounds (512 thr * 8 f16)
  constexpr int RB  = BSZ / 4096;         // B stage rounds
  constexpr int NLD = RA + RB;            // glds per tile
  __shared__ f16 lds[3 * (ASZ + BSZ)];    // 72 KB (256x128) / 48 KB (128x128)
  f16* As = lds;
  f16* Bs = lds + 3 * ASZ;

  const int t = threadIdx.x;

  // XCD-aware swizzle (nwg % 8 == 0 for all our grids)
  const int nwg = gridDim.x;
  const int bid = blockIdx.x;
  const int swz = (bid & 7) * (nwg >> 3) + (bid >> 3);
  const int bx = swz % GX;
  const int by = swz / GX;
  const int m0 = by * BM;
  const int n0 = bx * BN;

  // staging: LDS dest linear; XOR swizzle (chunk ^= row&3, 4 chunks per
  // 64B row) pre-applied to the GLOBAL source (rule 21).
  auto stage_all = [&](int kt, int buf) {
    const int k0 = kt << 5;
#pragma unroll
    for (int q = 0; q < RA; ++q) {
      int F = q * 4096 + t * 8;
      int r = F >> 5, c = (F >> 3) & 3;
      GLD16(A + (size_t)(m0 + r) * K + k0 + ((c ^ (r & 3)) << 3), As + buf * ASZ + F);
    }
#pragma unroll
    for (int q = 0; q < RB; ++q) {
      int F = q * 4096 + t * 8;
      int r = F >> 5, c = (F >> 3) & 3;
      GLD16(BT + (size_t)(n0 + r) * K + k0 + ((c ^ (r & 3)) << 3), Bs + buf * BSZ + F);
    }
  };

  const int wave = t >> 6, lane = t & 63;
  const int wr = wave / WN, wc = wave % WN;
  const int l16 = lane & 15, kq = lane >> 4;

  f32x4 acc[MR][NR] = {};

  const int nt = K >> 5;
  stage_all(0, 0);
  stage_all(1, 1);
  int cur = 0;
  for (int kt = 0; kt < nt; ++kt) {
    if (kt + 1 < nt) {
      // tile kt's NLD retired; tile kt+1's stay in flight (no drain)
      asm volatile("s_waitcnt vmcnt(%0)" :: "i"(NLD) : "memory");
    } else {
      asm volatile("s_waitcnt vmcnt(0)" ::: "memory");
    }
    __builtin_amdgcn_s_barrier();
    if (kt + 2 < nt) {
      int sb = cur + 2; if (sb >= 3) sb -= 3;
      stage_all(kt + 2, sb);              // issue first: longest latency
    }

    const f16* Ab = As + cur * ASZ;
    const f16* Bb = Bs + cur * BSZ;
    f16x8 a[MR], b[NR];
#pragma unroll
    for (int mr = 0; mr < MR; ++mr) {
      int row = wr * (MR * 16) + mr * 16 + l16;
      a[mr] = *(const f16x8*)&Ab[row * 32 + ((kq ^ (row & 3)) << 3)];
    }
#pragma unroll
    for (int nr = 0; nr < NR; ++nr) {
      int row = wc * (NR * 16) + nr * 16 + l16;
      b[nr] = *(const f16x8*)&Bb[row * 32 + ((kq ^ (row & 3)) << 3)];
    }
    asm volatile("s_waitcnt lgkmcnt(0)" ::: "memory");
    __builtin_amdgcn_sched_barrier(0);
    __builtin_amdgcn_s_setprio(1);
#pragma unroll
    for (int mr = 0; mr < MR; ++mr)
#pragma unroll
      for (int nr = 0; nr < NR; ++nr)
        acc[mr][nr] = __builtin_amdgcn_mfma_f32_16x16x32_f16(a[mr], b[nr], acc[mr][nr], 0, 0, 0);
    __builtin_amdgcn_s_setprio(0);
    cur = (cur + 1 == 3) ? 0 : cur + 1;
  }

  // epilogue: 16x16 C/D layout col=lane&15, row=(lane>>4)*4+q
#pragma unroll
  for (int nr = 0; nr < NR; ++nr) {
    const int col = n0 + wc * (NR * 16) + nr * 16 + l16;
    float bn = bias[col];
    if (EPI == 1) bn += prob[col];
#pragma unroll
    for (int mr = 0; mr < MR; ++mr) {
      const int rbase = m0 + wr * (MR * 16) + mr * 16 + kq * 4;
#pragma unroll
      for (int q = 0; q < 4; ++q) {
        float v = acc[mr][nr][q] + bn;
        if (EPI == 1) v = tanh_fast(v);
        else v = fmaxf(v, 0.0f);
        if (EPI == 2) Cf[(size_t)(rbase + q) * N + col] = v;
        else Ch[(size_t)(rbase + q) * N + col] = (f16)v;
      }
    }
  }
}

extern "C" void kernel_launch(void* const* d_in, const int* in_sizes, int n_in,
                              void* d_out, int out_size, void* d_ws, size_t ws_size,
                              hipStream_t stream) {
  const float* x   = (const float*)d_in[0];
  const float* W0  = (const float*)d_in[1];
  const float* b0  = (const float*)d_in[2];
  const float* W1  = (const float*)d_in[3];
  const float* b1  = (const float*)d_in[4];
  const float* cw1 = (const float*)d_in[5];
  const float* KW1 = (const float*)d_in[7];
  const float* Kb1 = (const float*)d_in[8];
  const float* W2  = (const float*)d_in[9];
  const float* b2  = (const float*)d_in[10];
  const float* cw2 = (const float*)d_in[11];
  const float* KW2 = (const float*)d_in[13];
  const float* Kb2 = (const float*)d_in[14];
  const float* W3  = (const float*)d_in[15];
  const float* b3  = (const float*)d_in[16];

  const int B = 4096, IN = 1024, H = 2048, OUT = 1024;

  char* ws = (char*)d_ws;
  size_t off = 0;
  auto alloc = [&](size_t bytes) {
    char* p = ws + off;
    off = (off + bytes + 255) & ~(size_t)255;
    return p;
  };
  f16* xh    = (f16*)alloc((size_t)B * IN * 2);
  f16* W0T   = (f16*)alloc((size_t)H * IN * 2);
  f16* W1T   = (f16*)alloc((size_t)H * H * 2);
  f16* KW1T  = (f16*)alloc((size_t)H * H * 2);
  f16* W2T   = (f16*)alloc((size_t)H * H * 2);
  f16* KW2T  = (f16*)alloc((size_t)H * H * 2);
  f16* W3T   = (f16*)alloc((size_t)OUT * H * 2);
  f16* hA    = (f16*)alloc((size_t)B * H * 2);
  f16* hB    = (f16*)alloc((size_t)B * H * 2);
  float* p1  = (float*)alloc((size_t)H * 4);
  float* p2  = (float*)alloc((size_t)H * 4);
  float* pp  = (float*)alloc((size_t)16 * H * 4);
  (void)ws_size;

  cast_f32_f16<<<(B * IN / 4 + 255) / 256, 256, 0, stream>>>(x, xh, B * IN / 4);

  TD6 td;
  td.d[0] = { W0,  W0T,  IN, H };
  td.d[1] = { W1,  W1T,  H,  H };
  td.d[2] = { KW1, KW1T, H,  H };
  td.d[3] = { W2,  W2T,  H,  H };
  td.d[4] = { KW2, KW2T, H,  H };
  td.d[5] = { W3,  W3T,  H,  OUT };
  cast_transpose6<<<dim3(H / 64, H / 32, 6), 256, 0, stream>>>(td);

  cosmic_pp2<<<(16 * H + 255) / 256, 256, 0, stream>>>(cw1, cw2, pp, H);
  cosmic_fin2<<<(2 * H + 255) / 256, 256, 0, stream>>>(pp, p1, p2, H);

  // G0-G4: 256x128 tile, 8 waves 4Mx2N (per-wave 64x64), 72 KB LDS,
  //        grid 16x16=256 -> 2 blocks/CU. (512,4) caps VGPR at 128.
  {
    int gx = H / 128, gy = B / 256;
    dim3 g(gx * gy);
    gemm_f16<0, 256, 128, 4, 2, 4><<<g, 512, 0, stream>>>(xh, W0T, b0,  nullptr, hA, nullptr, B, H, IN, gx);
    gemm_f16<0, 256, 128, 4, 2, 4><<<g, 512, 0, stream>>>(hA, W1T, b1,  nullptr, hB, nullptr, B, H, H,  gx);
    gemm_f16<1, 256, 128, 4, 2, 4><<<g, 512, 0, stream>>>(hB, KW1T, Kb1, p1,     hA, nullptr, B, H, H,  gx);
    gemm_f16<0, 256, 128, 4, 2, 4><<<g, 512, 0, stream>>>(hA, W2T, b2,  nullptr, hB, nullptr, B, H, H,  gx);
    gemm_f16<1, 256, 128, 4, 2, 4><<<g, 512, 0, stream>>>(hB, KW2T, Kb2, p2,     hA, nullptr, B, H, H,  gx);
  }
  // G5: N=1024 -> 128x128 tile, 8 waves 2Mx4N (per-wave 64x32), 48 KB LDS,
  //     grid 8x32=256 (full machine, 1 block/CU, 2 waves/SIMD).
  {
    int gx = OUT / 128, gy = B / 128;
    dim3 g(gx * gy);
    gemm_f16<2, 128, 128, 2, 4, 2><<<g, 512, 0, stream>>>(hA, W3T, b3, nullptr, nullptr, (float*)d_out, B, OUT, H, gx);
  }
}

// Round 9
// 211.875 us; speedup vs baseline: 1.1783x; 1.1783x over previous
//
#include <hip/hip_runtime.h>
#include <math.h>

// B=4096, IN=1024, H=2048, OUT=1024
// cosmic layer == broadcast prob[r] = (1/H)*(prod_{d,k} cos(cw[d,r,k]))^2
// Network = 6 fp16-MFMA GEMMs (16x16x32) with fused bias/relu/tanh epilogues.
//
// r9: conflict-free BK=64 layout (128B rows, XOR r&7 -> 2 lanes/bank = free)
// + 2 blocks/CU TLP (m97/m114 mechanism). 128x128 tile, 256 thr (4 waves
// 2x2, per-wave 64x64), double-buffered LDS 64 KB, counted vmcnt(8) (T4),
// 2 barriers per K-tile, stage issued mid-tile (full-cluster slack),
// setprio (T5), XOR-swizzle both-sides (T2/rule 21), XCD swizzle (T1).

typedef _Float16 f16;
typedef _Float16 f16x8 __attribute__((ext_vector_type(8)));
typedef _Float16 f16x4 __attribute__((ext_vector_type(4)));
typedef float f32x4 __attribute__((ext_vector_type(4)));

#define GLD16(gp, lp) __builtin_amdgcn_global_load_lds( \
    (const __attribute__((address_space(1))) unsigned int*)(gp), \
    (__attribute__((address_space(3))) unsigned int*)(lp), 16, 0, 0)

__device__ __forceinline__ float tanh_fast(float x) {
  return 1.0f - 2.0f / (__expf(2.0f * x) + 1.0f);
}

// ---------------- fp32 -> fp16 cast ----------------
__global__ void cast_f32_f16(const float* __restrict__ in, f16* __restrict__ out, int n4) {
  int i = blockIdx.x * 256 + threadIdx.x;
  if (i < n4) {
    float4 v = ((const float4*)in)[i];
    f16x4 o = { (f16)v.x, (f16)v.y, (f16)v.z, (f16)v.w };
    ((f16x4*)out)[i] = o;
  }
}

// ------- merged cast+transpose, vectorized: 32(K) x 64(N) f32 tiles -------
struct TD { const float* src; f16* dst; int K; int N; };
struct TD6 { TD d[6]; };

__global__ void cast_transpose6(TD6 a) {
  TD d = a.d[blockIdx.z];
  const int bx = blockIdx.x * 64;   // N
  const int by = blockIdx.y * 32;   // K
  if (bx >= d.N || by >= d.K) return;
  __shared__ float tile[32][68];
  const int t = threadIdx.x;
#pragma unroll
  for (int pass = 0; pass < 2; ++pass) {
    int idx = t + pass * 256;
    int row = idx >> 4;
    int c4  = (idx & 15) * 4;
    float4 v = *(const float4*)&d.src[(size_t)(by + row) * d.N + bx + c4];
    *(float4*)&tile[row][c4] = v;
  }
  __syncthreads();
  const int nl = t >> 2;
  const int k8 = (t & 3) * 8;
  f16x8 o;
#pragma unroll
  for (int j = 0; j < 8; ++j) o[j] = (f16)tile[k8 + j][nl];
  *(f16x8*)&d.dst[(size_t)(bx + nl) * d.K + by + k8] = o;
}

// ---------------- cosmic prob, 2-pass, both tensors fused ----------------
__global__ void cosmic_pp2(const float* __restrict__ cw1, const float* __restrict__ cw2,
                           float* __restrict__ pp, int H) {
  int i = blockIdx.x * 256 + threadIdx.x;   // 0 .. 16H
  if (i >= 16 * H) return;
  const float* cw = (i < 8 * H) ? cw1 : cw2;
  int j = (i < 8 * H) ? i : i - 8 * H;
  const float* a = cw + (size_t)j * H;
  pp[i] = cosf(a[0]) * cosf(a[1]) * cosf(a[2]);
}
__global__ void cosmic_fin2(const float* __restrict__ pp, float* __restrict__ p1,
                            float* __restrict__ p2, int H) {
  int r = blockIdx.x * 256 + threadIdx.x;   // 0 .. 2H
  if (r >= 2 * H) return;
  int rr = (r < H) ? r : r - H;
  const float* base = pp + ((r < H) ? 0 : 8 * H);
  float p = 1.0f;
#pragma unroll
  for (int d = 0; d < 8; ++d) p *= base[d * H + rr];
  float v = p * p / (float)H;
  if (r < H) p1[rr] = v; else p2[rr] = v;
}

// ---------------- fp16 MFMA GEMM (16x16x32), BK=64, dbuf, 2 blk/CU ----------------
// A: (M,K) f16 row-major. BT: (N,K) f16 row-major.
// EPI 0: relu->f16  1: tanh(+prob)->f16  2: relu->f32
// 256 thr = 4 waves (2M x 2N); per-wave (BM/2) x (BN/2).
template <int EPI, int BM, int BN, int MINW>
__global__ __launch_bounds__(256, MINW)
void gemm_f16(const f16* __restrict__ A, const f16* __restrict__ BT,
              const float* __restrict__ bias, const float* __restrict__ prob,
              f16* __restrict__ Ch, float* __restrict__ Cf,
              int M, int N, int K, int GX) {
  constexpr int ASZ = BM * 64;            // f16 per A buffer (BK=64)
  constexpr int BSZ = BN * 64;            // f16 per B buffer
  constexpr int MR  = BM / 32;            // A frag repeats per wave
  constexpr int NR  = BN / 32;            // B frag repeats per wave
  constexpr int RA  = ASZ / 2048;         // A stage rounds (256 thr * 8 f16)
  constexpr int RB  = BSZ / 2048;         // B stage rounds
  constexpr int NLD = RA + RB;            // glds per tile
  __shared__ f16 lds[2 * (ASZ + BSZ)];    // 64 KB (128x128) / 48 KB (128x64)
  f16* As = lds;
  f16* Bs = lds + 2 * ASZ;

  const int t = threadIdx.x;

  // XCD-aware swizzle (nwg % 8 == 0 for all our grids)
  const int nwg = gridDim.x;
  const int bid = blockIdx.x;
  const int swz = (bid & 7) * (nwg >> 3) + (bid >> 3);
  const int bx = swz % GX;
  const int by = swz / GX;
  const int m0 = by * BM;
  const int n0 = bx * BN;

  // staging: LDS dest linear (wave lanes -> consecutive 16B); XOR swizzle
  // (chunk ^= row&7, 8 chunks per 128B row) pre-applied to GLOBAL source
  // (rule 21). Each row = one permuted-within-128B coalesced segment.
  auto stage_all = [&](int kt, int buf) {
    const int k0 = kt << 6;
#pragma unroll
    for (int q = 0; q < RA; ++q) {
      int F = q * 2048 + t * 8;
      int r = F >> 6, c = (F >> 3) & 7;
      GLD16(A + (size_t)(m0 + r) * K + k0 + ((c ^ (r & 7)) << 3), As + buf * ASZ + F);
    }
#pragma unroll
    for (int q = 0; q < RB; ++q) {
      int F = q * 2048 + t * 8;
      int r = F >> 6, c = (F >> 3) & 7;
      GLD16(BT + (size_t)(n0 + r) * K + k0 + ((c ^ (r & 7)) << 3), Bs + buf * BSZ + F);
    }
  };

  const int wave = t >> 6, lane = t & 63;
  const int wr = wave >> 1, wc = wave & 1;   // 2M x 2N
  const int l16 = lane & 15, kq = lane >> 4;

  f32x4 acc[MR][NR] = {};

  const int nt = K >> 6;
  stage_all(0, 0);
  stage_all(1, 1);
  int cur = 0;
  for (int kt = 0; kt < nt; ++kt) {
    // tile kt's loads retired; tile kt+1's NLD stay in flight
    if (kt + 1 < nt) asm volatile("s_waitcnt vmcnt(%0)" :: "i"(NLD) : "memory");
    else             asm volatile("s_waitcnt vmcnt(0)" ::: "memory");
    __builtin_amdgcn_s_barrier();

    const f16* Ab = As + cur * ASZ;
    const f16* Bb = Bs + cur * BSZ;
    f16x8 a[2][MR], b[2][NR];
#pragma unroll
    for (int s = 0; s < 2; ++s) {
      const int cc = s * 4 + kq;          // 16B chunk (8 per 128B row)
#pragma unroll
      for (int mr = 0; mr < MR; ++mr) {
        int row = wr * (MR * 16) + mr * 16 + l16;
        a[s][mr] = *(const f16x8*)&Ab[row * 64 + ((cc ^ (row & 7)) << 3)];
      }
#pragma unroll
      for (int nr = 0; nr < NR; ++nr) {
        int row = wc * (NR * 16) + nr * 16 + l16;
        b[s][nr] = *(const f16x8*)&Bb[row * 64 + ((cc ^ (row & 7)) << 3)];
      }
      __builtin_amdgcn_sched_barrier(0);  // pin: s0 reads issue before s1
    }
    // cluster 0: wait s0's reads (s1's stay outstanding under MFMA)
    asm volatile("s_waitcnt lgkmcnt(%0)" :: "i"(MR + NR) : "memory");
    __builtin_amdgcn_sched_barrier(0);
    __builtin_amdgcn_s_setprio(1);
#pragma unroll
    for (int mr = 0; mr < MR; ++mr)
#pragma unroll
      for (int nr = 0; nr < NR; ++nr)
        acc[mr][nr] = __builtin_amdgcn_mfma_f32_16x16x32_f16(a[0][mr], b[0][nr], acc[mr][nr], 0, 0, 0);
    __builtin_amdgcn_s_setprio(0);
    // all reads of buf cur complete in every wave -> safe to overwrite after bar
    asm volatile("s_waitcnt lgkmcnt(0)" ::: "memory");
    __builtin_amdgcn_sched_barrier(0);
    __builtin_amdgcn_s_barrier();
    if (kt + 2 < nt) stage_all(kt + 2, cur);   // into just-freed buffer
    __builtin_amdgcn_s_setprio(1);
#pragma unroll
    for (int mr = 0; mr < MR; ++mr)
#pragma unroll
      for (int nr = 0; nr < NR; ++nr)
        acc[mr][nr] = __builtin_amdgcn_mfma_f32_16x16x32_f16(a[1][mr], b[1][nr], acc[mr][nr], 0, 0, 0);
    __builtin_amdgcn_s_setprio(0);
    cur ^= 1;
  }

  // epilogue: 16x16 C/D layout col=lane&15, row=(lane>>4)*4+q
#pragma unroll
  for (int nr = 0; nr < NR; ++nr) {
    const int col = n0 + wc * (NR * 16) + nr * 16 + l16;
    float bn = bias[col];
    if (EPI == 1) bn += prob[col];
#pragma unroll
    for (int mr = 0; mr < MR; ++mr) {
      const int rbase = m0 + wr * (MR * 16) + mr * 16 + kq * 4;
#pragma unroll
      for (int q = 0; q < 4; ++q) {
        float v = acc[mr][nr][q] + bn;
        if (EPI == 1) v = tanh_fast(v);
        else v = fmaxf(v, 0.0f);
        if (EPI == 2) Cf[(size_t)(rbase + q) * N + col] = v;
        else Ch[(size_t)(rbase + q) * N + col] = (f16)v;
      }
    }
  }
}

extern "C" void kernel_launch(void* const* d_in, const int* in_sizes, int n_in,
                              void* d_out, int out_size, void* d_ws, size_t ws_size,
                              hipStream_t stream) {
  const float* x   = (const float*)d_in[0];
  const float* W0  = (const float*)d_in[1];
  const float* b0  = (const float*)d_in[2];
  const float* W1  = (const float*)d_in[3];
  const float* b1  = (const float*)d_in[4];
  const float* cw1 = (const float*)d_in[5];
  const float* KW1 = (const float*)d_in[7];
  const float* Kb1 = (const float*)d_in[8];
  const float* W2  = (const float*)d_in[9];
  const float* b2  = (const float*)d_in[10];
  const float* cw2 = (const float*)d_in[11];
  const float* KW2 = (const float*)d_in[13];
  const float* Kb2 = (const float*)d_in[14];
  const float* W3  = (const float*)d_in[15];
  const float* b3  = (const float*)d_in[16];

  const int B = 4096, IN = 1024, H = 2048, OUT = 1024;

  char* ws = (char*)d_ws;
  size_t off = 0;
  auto alloc = [&](size_t bytes) {
    char* p = ws + off;
    off = (off + bytes + 255) & ~(size_t)255;
    return p;
  };
  f16* xh    = (f16*)alloc((size_t)B * IN * 2);
  f16* W0T   = (f16*)alloc((size_t)H * IN * 2);
  f16* W1T   = (f16*)alloc((size_t)H * H * 2);
  f16* KW1T  = (f16*)alloc((size_t)H * H * 2);
  f16* W2T   = (f16*)alloc((size_t)H * H * 2);
  f16* KW2T  = (f16*)alloc((size_t)H * H * 2);
  f16* W3T   = (f16*)alloc((size_t)OUT * H * 2);
  f16* hA    = (f16*)alloc((size_t)B * H * 2);
  f16* hB    = (f16*)alloc((size_t)B * H * 2);
  float* p1  = (float*)alloc((size_t)H * 4);
  float* p2  = (float*)alloc((size_t)H * 4);
  float* pp  = (float*)alloc((size_t)16 * H * 4);
  (void)ws_size;

  cast_f32_f16<<<(B * IN / 4 + 255) / 256, 256, 0, stream>>>(x, xh, B * IN / 4);

  TD6 td;
  td.d[0] = { W0,  W0T,  IN, H };
  td.d[1] = { W1,  W1T,  H,  H };
  td.d[2] = { KW1, KW1T, H,  H };
  td.d[3] = { W2,  W2T,  H,  H };
  td.d[4] = { KW2, KW2T, H,  H };
  td.d[5] = { W3,  W3T,  H,  OUT };
  cast_transpose6<<<dim3(H / 64, H / 32, 6), 256, 0, stream>>>(td);

  cosmic_pp2<<<(16 * H + 255) / 256, 256, 0, stream>>>(cw1, cw2, pp, H);
  cosmic_fin2<<<(2 * H + 255) / 256, 256, 0, stream>>>(pp, p1, p2, H);

  // G0-G4: 128x128 tile, 64 KB LDS, grid 16x32=512 -> 2 blocks/CU.
  {
    int gx = H / 128, gy = B / 128;
    dim3 g(gx * gy);
    gemm_f16<0, 128, 128, 2><<<g, 256, 0, stream>>>(xh, W0T, b0,  nullptr, hA, nullptr, B, H, IN, gx);
    gemm_f16<0, 128, 128, 2><<<g, 256, 0, stream>>>(hA, W1T, b1,  nullptr, hB, nullptr, B, H, H,  gx);
    gemm_f16<1, 128, 128, 2><<<g, 256, 0, stream>>>(hB, KW1T, Kb1, p1,     hA, nullptr, B, H, H,  gx);
    gemm_f16<0, 128, 128, 2><<<g, 256, 0, stream>>>(hA, W2T, b2,  nullptr, hB, nullptr, B, H, H,  gx);
    gemm_f16<1, 128, 128, 2><<<g, 256, 0, stream>>>(hB, KW2T, Kb2, p2,     hA, nullptr, B, H, H,  gx);
  }
  // G5: 128x64 tile, 48 KB LDS, grid 16x32=512 -> up to 3 blocks/CU.
  {
    int gx = OUT / 64, gy = B / 128;
    dim3 g(gx * gy);
    gemm_f16<2, 128, 64, 3><<<g, 256, 0, stream>>>(hA, W3T, b3, nullptr, nullptr, (float*)d_out, B, OUT, H, gx);
  }
}